// Round 4
// baseline (949.747 us; speedup 1.0000x reference)
//
#include <hip/hip_runtime.h>
#include <cstdint>
#include <cstring>

// VQR circuit simulator: 16 qubits, B=512, 4 layers.
// CNOTs are GF(2) index-relabeling bookkeeping. Fused 1q gates (exact SU(2))
// are XOR-mask pair rotations on LDS-resident chunks. Host searches window
// pairs + exact-commutation schedule to minimize full-state passes (target 2:
// gen+gates+store, load+gates+measure). Excluded wires sit at bit positions
// >=8 so global accesses are >=2KB-contiguous runs.

struct PassMeta {
    int      nclusters;
    uint16_t cx[24], cy[24];     // coset basis (local-index XOR masks)
    uint16_t rowA[24], rowB[24]; // branch parity masks (local bits)
    uint8_t  cq0[24], cq1[24];   // pivot bit positions, ascending
    uint8_t  gA[24], gB[24];     // gate matrix index l*16+w; 0xFF -> identity
    uint8_t  nlA[24], nlB[24];   // branch parity masks over chunk bits
    uint8_t  pyA[24];            // parity(y & rowA): beta flip of A's 2nd pair
    uint8_t  patB[24];           // B pairing: 0:(01)(23) 1:(02)(13) 2:(03)(12)
    uint8_t  poffB[24];          // beta flip for B's 2nd pair
    uint8_t  gap[4];             // non-local bit positions, ASCENDING (all >=8)
    uint8_t  wire_of_bit[13];    // packed LDS bit -> wire (product-state init)
    uint8_t  nlw[4];             // chunk bit k -> wire (aligned with gap[k])
    uint16_t meas_row_local;     // measurement parity mask (local bits)
    uint8_t  meas_nl;            // measurement parity mask (chunk bits)
};

__device__ __forceinline__ float2 cmul2(float2 a, float2 b) {
    return make_float2(a.x * b.x - a.y * b.y, a.x * b.y + a.y * b.x);
}

// SU(2) gate u=(ar,ai,br,bi) meaning [[a,b],[-conj(b),conj(a)]].
// s = 0 or 0x80000000 selects p as the |0> (s=0) or |1> (s=sign) amplitude.
// Conjugation-by-X == sign flips on a.im and b.re -> 2 XOR + 16 FMA, no cndmask.
__device__ __forceinline__ void apply_pair(float2& p, float2& q, unsigned s,
                                           const float4& u) {
    float tai = __uint_as_float(__float_as_uint(u.y) ^ s);
    float tbr = __uint_as_float(__float_as_uint(u.z) ^ s);
    float npr = u.x * p.x - tai * p.y + tbr * q.x - u.w * q.y;
    float npi = u.x * p.y + tai * p.x + tbr * q.y + u.w * q.x;
    float nqr = -tbr * p.x - u.w * p.y + u.x * q.x + tai * q.y;
    float nqi = -tbr * p.y + u.w * p.x + u.x * q.y - tai * q.x;
    p = make_float2(npr, npi);
    q = make_float2(nqr, nqi);
}

// Fused U = Rz(t2)Ry(t1)Rz(t0)Rx(enc), enc = 2*atan(x). Store (a,b) only
// (SU(2) exact): Ug[b*64 + l*16 + w] = (a.re, a.im, b.re, b.im).
__global__ __launch_bounds__(512)
void precompute_kernel(const float* __restrict__ X, const float* __restrict__ Wt,
                       const float* __restrict__ Bs, float4* __restrict__ Ug,
                       float* __restrict__ out)
{
    int id = blockIdx.x * 512 + threadIdx.x;
    if (id >= 512 * 64) return;
    int b = id >> 6, lw = id & 63, l = lw >> 4, w = lw & 15;
    float x  = X[b * 16 + w];
    float ce = 1.0f / sqrtf(1.0f + x * x);
    float se = x * ce;
    float t0 = 0.5f * Wt[(l * 16 + w) * 3 + 0];
    float t1 = 0.5f * Wt[(l * 16 + w) * 3 + 1];
    float t2 = 0.5f * Wt[(l * 16 + w) * 3 + 2];
    float c1 = cosf(t1), s1 = sinf(t1);
    float ca = cosf(t0 + t2), sa = sinf(t0 + t2);
    float cb = cosf(t2 - t0), sb = sinf(t2 - t0);
    float2 W00 = make_float2( c1 * ca, -c1 * sa);
    float2 W01 = make_float2(-s1 * cb,  s1 * sb);
    // U00 = W00*ce + W01*(-i se); U01 = W00*(-i se) + W01*ce
    float2 a = make_float2(W00.x * ce + W01.y * se, W00.y * ce - W01.x * se);
    float2 bb = make_float2(W00.y * se + W01.x * ce, -W00.x * se + W01.y * ce);
    Ug[id] = make_float4(a.x, a.y, bb.x, bb.y);
    if (lw == 0) out[b] = Bs[0];
}

// MODE 0: generate product state + gates + store
// MODE 1: load + gates + store (in-place)
// MODE 2: load + gates + measurement reduce (no store)
template <int MODE, int LB>
__global__ __launch_bounds__(512)
void pass_kernel(const float4* __restrict__ Ug, float2* __restrict__ state,
                 float* __restrict__ out, PassMeta meta)
{
    constexpr int AMPS = 1 << LB;
    constexpr int NCH  = 16 - LB;
    __shared__ float2 amp[AMPS];
    const int tid = threadIdx.x;
    const int bb  = blockIdx.x >> NCH;
    const unsigned c = blockIdx.x & ((1u << NCH) - 1u);
    const size_t base = ((size_t)bb) << 16;
    const float4* Ub = Ug + (size_t)bb * 64;

    auto expand = [&](unsigned x) -> unsigned {   // gaps ascending, all >= 8
        #pragma unroll
        for (int k = 0; k < NCH; ++k) {
            unsigned g = meta.gap[k];
            x = ((x >> g) << (g + 1)) | (x & ((1u << g) - 1u)) | (((c >> k) & 1u) << g);
        }
        return x;
    };

    if constexpr (MODE == 0) {
        if (tid == 0) {
            float2 k = make_float2(1.f, 0.f);
            for (int t = 0; t < NCH; ++t) {
                float4 u = Ub[(int)meta.nlw[t]];
                float2 col = ((c >> t) & 1u) ? make_float2(-u.z, u.w)
                                             : make_float2(u.x, u.y);
                k = cmul2(k, col);
            }
            amp[0] = k;
        }
        __syncthreads();
        for (int s = 0; s < LB; ++s) {
            const int n = 1 << s;
            float4 u = Ub[(int)meta.wire_of_bit[s]];
            const float2 c0 = make_float2(u.x, u.y);   // U00
            const float2 c1 = make_float2(-u.z, u.w);  // U10 = -conj(b)
            for (int i = tid; i < n; i += 512) {
                float2 a = amp[i];
                amp[i + n] = cmul2(a, c1);
                amp[i]     = cmul2(a, c0);
            }
            __syncthreads();
        }
    } else {
        constexpr int LIT = AMPS / 1024;
        #pragma unroll
        for (int it = 0; it < LIT; ++it) {
            unsigned u = (unsigned)(tid + it * 512) * 2u;
            unsigned a = expand(u);
            float4 v = *reinterpret_cast<const float4*>(state + base + a);
            amp[u]     = make_float2(v.x, v.y);
            amp[u + 1] = make_float2(v.z, v.w);
        }
        __syncthreads();
    }

    for (int ci = 0; ci < meta.nclusters; ++ci) {
        const unsigned x = meta.cx[ci], y = meta.cy[ci];
        const unsigned q0 = meta.cq0[ci], q1 = meta.cq1[ci];
        const float4 A = Ub[(int)meta.gA[ci]];
        const float4 B = (meta.gB[ci] != 0xFF) ? Ub[(int)meta.gB[ci]]
                                               : make_float4(1.f, 0.f, 0.f, 0.f);
        const unsigned rowA = meta.rowA[ci], rowB = meta.rowB[ci];
        const unsigned baseA = (unsigned)(__popc((unsigned)meta.nlA[ci] & c) & 1) << 31;
        const unsigned baseB = (unsigned)(__popc((unsigned)meta.nlB[ci] & c) & 1) << 31;
        const unsigned pyA31 = ((unsigned)meta.pyA[ci]) << 31;
        const unsigned poB31 = ((unsigned)meta.poffB[ci]) << 31;
        const unsigned pat = meta.patB[ci];
        constexpr int KIT = AMPS / 2048;
        #pragma unroll
        for (int k = 0; k < KIT; ++k) {
            unsigned pid = (unsigned)tid + (unsigned)k * 512u;
            unsigned r = ((pid >> q0) << (q0 + 1)) | (pid & ((1u << q0) - 1u));
            r = ((r >> q1) << (q1 + 1)) | (r & ((1u << q1) - 1u));
            float2 a0 = amp[r];
            float2 a1 = amp[r ^ x];
            float2 a2 = amp[r ^ y];
            float2 a3 = amp[r ^ x ^ y];
            unsigned sA = ((unsigned)(__popc(r & rowA) & 1) << 31) ^ baseA;
            apply_pair(a0, a1, sA, A);
            apply_pair(a2, a3, sA ^ pyA31, A);
            unsigned sB = ((unsigned)(__popc(r & rowB) & 1) << 31) ^ baseB;
            if (pat == 0)      { apply_pair(a0, a1, sB, B); apply_pair(a2, a3, sB ^ poB31, B); }
            else if (pat == 1) { apply_pair(a0, a2, sB, B); apply_pair(a1, a3, sB ^ poB31, B); }
            else               { apply_pair(a0, a3, sB, B); apply_pair(a1, a2, sB ^ poB31, B); }
            amp[r]         = a0;
            amp[r ^ x]     = a1;
            amp[r ^ y]     = a2;
            amp[r ^ x ^ y] = a3;
        }
        __syncthreads();
    }

    if constexpr (MODE == 2) {
        float acc = 0.f;
        const unsigned mrow = meta.meas_row_local;
        const unsigned mbp  = (unsigned)(__popc((unsigned)meta.meas_nl & c) & 1);
        constexpr int MIT = AMPS / 512;
        #pragma unroll
        for (int k = 0; k < MIT; ++k) {
            const unsigned u = (unsigned)(tid + k * 512);
            const float2 a = amp[u];
            const float t = a.x * a.x + a.y * a.y;
            acc += ((__popc(u & mrow) + mbp) & 1) ? -t : t;
        }
        for (int off = 32; off > 0; off >>= 1) acc += __shfl_down(acc, off, 64);
        if ((tid & 63) == 0) atomicAdd(&out[bb], acc);
    } else {
        constexpr int LIT = AMPS / 1024;
        #pragma unroll
        for (int it = 0; it < LIT; ++it) {
            unsigned u = (unsigned)(tid + it * 512) * 2u;
            unsigned a = expand(u);
            float2 lo = amp[u], hi = amp[u + 1];
            float4 v = make_float4(lo.x, lo.y, hi.x, hi.y);
            *reinterpret_cast<float4*>(state + base + a) = v;
        }
    }
}

extern "C" void kernel_launch(void* const* d_in, const int* in_sizes, int n_in,
                              void* d_out, int out_size, void* d_ws, size_t ws_size,
                              hipStream_t stream)
{
    const float* X  = (const float*)d_in[0];
    const float* Wt = (const float*)d_in[1];
    const float* Bs = (const float*)d_in[2];
    float* out = (float*)d_out;

    const size_t UG_BYTES = (size_t)512 * 64 * sizeof(float4);  // 512 KiB
    float4* Ug    = (float4*)d_ws;
    float2* state = (float2*)((char*)d_ws + UG_BYTES);
    size_t avail = ws_size > UG_BYTES ? ws_size - UG_BYTES : 0;
    int group = 1;
    while (group < 512 && (size_t)(group * 2) * (65536ull * sizeof(float2)) <= avail)
        group <<= 1;
    const int ngroups = 512 / group;

    // ---- GF(2) bookkeeping (sequential CNOT ring, matches reference) ----
    uint16_t D[16], R[16];
    for (int w = 0; w < 16; ++w) { D[w] = R[w] = (uint16_t)(1u << w); }
    struct G { uint16_t D, R; uint8_t gidx; bool kept; bool sched; };
    G gl[48]; int ng = 0;
    for (int l = 1; l <= 3; ++l) {
        for (int w = 0; w < 16; ++w) { int t = (w + 1) & 15; D[w] ^= D[t]; R[t] ^= R[w]; }
        for (int w = 0; w < 16; ++w)
            gl[ng++] = G{D[w], R[w], (uint8_t)(l * 16 + w), true, false};
    }
    for (int w = 0; w < 16; ++w) { int t = (w + 1) & 15; D[w] ^= D[t]; R[t] ^= R[w]; }
    const uint16_t Rmeas = R[0];

    // Backward prune: drop gates commuting with every later kept op + observable.
    {
        uint16_t keptD[49], keptR[49]; int nk = 0;
        keptD[nk] = 0; keptR[nk] = Rmeas; ++nk;
        for (int i = ng - 1; i >= 0; --i) {
            bool comm = true;
            for (int k = 0; k < nk; ++k) {
                if (__builtin_parity((unsigned)(gl[i].D & keptR[k])) ||
                    __builtin_parity((unsigned)(keptD[k] & gl[i].R))) { comm = false; break; }
            }
            if (comm) gl[i].kept = false;
            else { keptD[nk] = gl[i].D; keptR[nk] = gl[i].R; ++nk; }
        }
    }
    int nkept = 0;
    for (int i = 0; i < ng; ++i) if (gl[i].kept) ++nkept;

    auto commute = [&](int i, int j) -> bool {
        return !(__builtin_parity((unsigned)(gl[i].D & gl[j].R)) ||
                 __builtin_parity((unsigned)(gl[j].D & gl[i].R)));
    };

    // Exact-commutation schedule simulator. Pass p uses window (p even: SA, odd: SB).
    // Gate placeable iff its D-support avoids the excluded wires AND it commutes
    // with every earlier still-unscheduled gate. Returns pass count (or 99).
    const int MAXP = 10;
    auto simulate = [&](uint16_t SA, uint16_t SB, int* passOf) -> int {
        for (int i = 0; i < ng; ++i) gl[i].sched = false;
        int rem = nkept, np = 0, stall = 0;
        while (rem > 0 && np < MAXP) {
            uint16_t S = (np & 1) ? SB : SA;
            int got = 0;
            for (int i = 0; i < ng; ++i) {
                if (!gl[i].kept || gl[i].sched) continue;
                if (gl[i].D & S) continue;
                bool ok = true;
                for (int j = 0; j < i; ++j) {
                    if (!gl[j].kept || gl[j].sched) continue;
                    if (!commute(i, j)) { ok = false; break; }
                }
                if (!ok) continue;
                gl[i].sched = true; --rem; ++got;
                if (passOf) passOf[i] = np;
            }
            ++np;
            if (got == 0) { if (++stall >= 2) break; } else stall = 0;
        }
        return rem == 0 ? np : 99;
    };

    // Search window pairs (consecutive wire runs) over LB in {12,13}.
    int bestNp = 99, bestLB = 13, bestA = 3, bestB = 11;
    for (int LB = 12; LB <= 13; ++LB) {
        int EX = 16 - LB;
        for (int a = 0; a < 16; ++a) {
            for (int b = 0; b < 16; ++b) {
                uint16_t SA = 0, SB = 0;
                for (int k = 0; k < EX; ++k) {
                    SA |= (uint16_t)(1u << ((a + k) & 15));
                    SB |= (uint16_t)(1u << ((b + k) & 15));
                }
                int np = simulate(SA, SB, nullptr);
                if (np < bestNp || (np == bestNp && LB < bestLB)) {
                    bestNp = np; bestLB = LB; bestA = a; bestB = b;
                }
            }
        }
    }
    const int LB = bestLB, EX = 16 - LB;
    uint16_t SA = 0, SB = 0;
    int exA[4], exB[4];
    for (int k = 0; k < EX; ++k) {
        exA[k] = (bestA + k) & 15; exB[k] = (bestB + k) & 15;
        SA |= (uint16_t)(1u << exA[k]); SB |= (uint16_t)(1u << exB[k]);
    }
    int passOf[48];
    for (int i = 0; i < ng; ++i) passOf[i] = -1;
    int np = simulate(SA, SB, passOf);
    if (np > MAXP) np = MAXP;        // unreachable; safety
    if (np < 2) np = 2;              // need a load+measure pass

    // Wire -> bit position: all excluded wires (both windows) at top positions
    // (>= 8 for LB=12) so global runs are contiguous and long.
    int wireToPos[16]; bool used[16] = {};
    int pos = 15;
    for (int k = 0; k < EX; ++k) { wireToPos[exA[k]] = pos--; used[exA[k]] = true; }
    for (int k = 0; k < EX; ++k)
        if (!used[exB[k]]) { wireToPos[exB[k]] = pos--; used[exB[k]] = true; }
    for (int w = 0; w < 16; ++w) if (!used[w]) wireToPos[w] = pos--;
    int posToWire[16];
    for (int w = 0; w < 16; ++w) posToWire[wireToPos[w]] = w;

    static PassMeta pms[10];
    for (int p = 0; p < np; ++p) {
        PassMeta& M = pms[p];
        memset(&M, 0, sizeof(M));
        const int* ex = (p & 1) ? exB : exA;
        // gap positions ascending, with matching wires
        int gp[4], gw[4];
        for (int k = 0; k < EX; ++k) { gp[k] = wireToPos[ex[k]]; gw[k] = ex[k]; }
        for (int a2 = 0; a2 < EX; ++a2)
            for (int b2 = a2 + 1; b2 < EX; ++b2)
                if (gp[b2] < gp[a2]) {
                    int t = gp[a2]; gp[a2] = gp[b2]; gp[b2] = t;
                    t = gw[a2]; gw[a2] = gw[b2]; gw[b2] = t;
                }
        for (int k = 0; k < EX; ++k) { M.gap[k] = (uint8_t)gp[k]; M.nlw[k] = (uint8_t)gw[k]; }
        int packedOfWire[16];
        for (int w = 0; w < 16; ++w) packedOfWire[w] = -1;
        int t = 0;
        for (int q = 0; q < 16; ++q) {
            bool isgap = false;
            for (int k = 0; k < EX; ++k) if (q == gp[k]) isgap = true;
            if (isgap) continue;
            int w = posToWire[q];
            M.wire_of_bit[t] = (uint8_t)w;
            packedOfWire[w] = t;
            ++t;
        }
        // gate list for this pass, circuit-selection order
        int sel[48], nsel = 0;
        for (int i = 0; i < ng; ++i)
            if (gl[i].kept && passOf[i] == p) sel[nsel++] = i;
        auto tolocal = [&](const G& g, uint16_t& m, uint16_t& r, uint8_t& nl) {
            m = 0; r = 0; nl = 0;
            for (int w = 0; w < 16; ++w) {
                if ((g.D >> w) & 1) m |= (uint16_t)(1u << packedOfWire[w]);
                if (((g.R >> w) & 1) && packedOfWire[w] >= 0)
                    r |= (uint16_t)(1u << packedOfWire[w]);
            }
            for (int k = 0; k < EX; ++k)
                if ((g.R >> gw[k]) & 1) nl |= (uint8_t)(1u << k);
        };
        M.nclusters = 0;
        for (int s = 0; s < nsel; s += 2) {
            int ci = M.nclusters++;
            uint16_t mA, rA; uint8_t nlA;
            tolocal(gl[sel[s]], mA, rA, nlA);
            bool hasB = (s + 1) < nsel;
            uint16_t mB = 0, rB = 0; uint8_t nlB = 0;
            if (hasB) tolocal(gl[sel[s + 1]], mB, rB, nlB);
            uint16_t xm = mA, ym; int pat;
            if (!hasB || mB == mA) {
                ym = (xm == 1u) ? 2u : 1u;
                pat = 0;
            } else {
                ym = mB;
                int px0 = 31 - __builtin_clz((unsigned)xm);
                if ((ym >> px0) & 1) { ym ^= xm; pat = 2; } else pat = 1;
            }
            int px = 31 - __builtin_clz((unsigned)xm);
            int py = 31 - __builtin_clz((unsigned)ym);
            int qa = px < py ? px : py, qb = px < py ? py : px;
            M.cx[ci] = xm; M.cy[ci] = ym;
            M.cq0[ci] = (uint8_t)qa; M.cq1[ci] = (uint8_t)qb;
            M.gA[ci] = gl[sel[s]].gidx;
            M.gB[ci] = hasB ? gl[sel[s + 1]].gidx : (uint8_t)0xFF;
            M.rowA[ci] = rA; M.nlA[ci] = nlA;
            M.rowB[ci] = hasB ? rB : (uint16_t)0;
            M.nlB[ci]  = hasB ? nlB : (uint8_t)0;
            M.pyA[ci]  = (uint8_t)__builtin_parity((unsigned)(ym & rA));
            M.patB[ci] = (uint8_t)pat;
            M.poffB[ci] = hasB
                ? (uint8_t)__builtin_parity((unsigned)(((pat == 0) ? ym : xm) & rB))
                : (uint8_t)0;
        }
        {   // measurement masks (used only if this pass is last)
            uint16_t r = 0; uint8_t nl = 0;
            for (int w = 0; w < 16; ++w)
                if (((Rmeas >> w) & 1) && packedOfWire[w] >= 0)
                    r |= (uint16_t)(1u << packedOfWire[w]);
            for (int k = 0; k < EX; ++k)
                if ((Rmeas >> gw[k]) & 1) nl |= (uint8_t)(1u << k);
            M.meas_row_local = r; M.meas_nl = nl;
        }
    }

    precompute_kernel<<<dim3(64), dim3(512), 0, stream>>>(X, Wt, Bs, Ug, out);
    for (int g = 0; g < ngroups; ++g) {
        const float4* ug = Ug + (size_t)g * group * 64;
        float* og = out + (size_t)g * group;
        dim3 grid((unsigned)(group << EX));
        for (int p = 0; p < np; ++p) {
            int mode = (p == 0) ? 0 : ((p == np - 1) ? 2 : 1);
            if (LB == 12) {
                if (mode == 0)
                    pass_kernel<0,12><<<grid, dim3(512), 0, stream>>>(ug, state, og, pms[p]);
                else if (mode == 1)
                    pass_kernel<1,12><<<grid, dim3(512), 0, stream>>>(ug, state, og, pms[p]);
                else
                    pass_kernel<2,12><<<grid, dim3(512), 0, stream>>>(ug, state, og, pms[p]);
            } else {
                if (mode == 0)
                    pass_kernel<0,13><<<grid, dim3(512), 0, stream>>>(ug, state, og, pms[p]);
                else if (mode == 1)
                    pass_kernel<1,13><<<grid, dim3(512), 0, stream>>>(ug, state, og, pms[p]);
                else
                    pass_kernel<2,13><<<grid, dim3(512), 0, stream>>>(ug, state, og, pms[p]);
            }
        }
    }

    (void)in_sizes; (void)n_in; (void)out_size; (void)ws_size;
}

// Round 5
// 685.563 us; speedup vs baseline: 1.3854x; 1.3854x over previous
//
#include <hip/hip_runtime.h>
#include <hip/hip_fp16.h>
#include <cstdint>
#include <cstring>

// VQR circuit simulator: 16 qubits, B=512, 4 layers.
// CNOTs are GF(2) index-relabeling bookkeeping. Fused 1q gates (SU(2)) are
// XOR-mask pair rotations. Host schedules gates into 2 window passes
// (gen+gates+store, load+gates+measure), and within a pass into bundles of
// 4 mask-independent gates; each thread applies a bundle on a dim-4 coset
// (16 amps) in registers. Intermediate state stored fp16 (error << thresh).

typedef float v2f __attribute__((ext_vector_type(2)));

struct BundleMeta {
    uint16_t voff[16];   // coset offsets (local 12-bit index space)
    uint16_t row[4];     // branch parity masks (local bits), per slot
    uint16_t flip[4];    // flip[g] bit t = parity(voff[t] & row[g])
    uint8_t  piv[4];     // pivot bit positions, ASCENDING (rep expansion)
    uint8_t  gidx[4];    // gate coefficient index l*16+w; 0xFF = identity pad
    uint8_t  nl[4];      // branch parity masks over the 4 chunk bits
};

struct PassMeta {
    int       nbundles;
    BundleMeta bd[24];
    uint8_t   gap[4];          // non-local bit positions, ASCENDING (all >=8)
    uint8_t   nlw[4];          // chunk bit k -> wire
    uint8_t   wire_of_bit[12]; // packed LDS bit -> wire (product-state init)
    uint16_t  meas_row;        // measurement parity mask (local bits)
    uint8_t   meas_nl;         // measurement parity mask (chunk bits)
};

__device__ __forceinline__ float2 cmul2(float2 a, float2 b) {
    return make_float2(a.x * b.x - a.y * b.y, a.x * b.y + a.y * b.x);
}
__device__ __forceinline__ float xorf(float a, unsigned s) {
    return __uint_as_float(__float_as_uint(a) ^ s);
}

// SU(2) gate u=(ar,ai,br,bi) == [[a,b],[-conj(b),conj(a)]]; s in {0,0x80000000}:
// s set means p is the |1>-branch. Packed-fp32 complex MACs, sign-XOR trick.
__device__ __forceinline__ void pair_xor(v2f& p, v2f& q, unsigned s, const float4& u) {
    float tai = xorf(u.y, s);
    float tbr = xorf(u.z, s);
    v2f A   = {u.x, tai};
    v2f Ar  = {-tai, u.x};
    v2f Bv  = {tbr, u.w};
    v2f Br  = {-u.w, tbr};
    v2f np  = A * p.x + Ar * p.y + Bv * q.x + Br * q.y;
    v2f Nb  = {-tbr, u.w};
    v2f Nbr = {-u.w, -tbr};
    v2f Ac  = {u.x, -tai};
    v2f Acr = {tai, u.x};
    v2f nq  = Nb * p.x + Nbr * p.y + Ac * q.x + Acr * q.y;
    p = np;
    q = nq;
}

// Fused U = Rz(t2)Ry(t1)Rz(t0)Rx(enc), enc = 2*atan(x); store (a,b) of SU(2).
__global__ __launch_bounds__(512)
void precompute_kernel(const float* __restrict__ X, const float* __restrict__ Wt,
                       const float* __restrict__ Bs, float4* __restrict__ Ug,
                       float* __restrict__ out)
{
    int id = blockIdx.x * 512 + threadIdx.x;
    if (id >= 512 * 64) return;
    int b = id >> 6, lw = id & 63, l = lw >> 4, w = lw & 15;
    float x  = X[b * 16 + w];
    float ce = 1.0f / sqrtf(1.0f + x * x);
    float se = x * ce;
    float t0 = 0.5f * Wt[(l * 16 + w) * 3 + 0];
    float t1 = 0.5f * Wt[(l * 16 + w) * 3 + 1];
    float t2 = 0.5f * Wt[(l * 16 + w) * 3 + 2];
    float c1 = cosf(t1), s1 = sinf(t1);
    float ca = cosf(t0 + t2), sa = sinf(t0 + t2);
    float cb = cosf(t2 - t0), sb = sinf(t2 - t0);
    float2 W00 = make_float2( c1 * ca, -c1 * sa);
    float2 W01 = make_float2(-s1 * cb,  s1 * sb);
    float2 a  = make_float2(W00.x * ce + W01.y * se, W00.y * ce - W01.x * se);
    float2 bb = make_float2(W00.y * se + W01.x * ce, -W00.x * se + W01.y * ce);
    Ug[id] = make_float4(a.x, a.y, bb.x, bb.y);
    if (lw == 0) out[b] = Bs[0];
}

// MODE 0: generate product state + gates + store (fp16)
// MODE 1: load + gates + store (in-place, fp16)
// MODE 2: load + gates + measurement reduce (no store)
template <int MODE>
__global__ __launch_bounds__(256)
void pass_kernel(const float4* __restrict__ Ug, __half2* __restrict__ state,
                 float* __restrict__ out, PassMeta meta)
{
    __shared__ v2f    amp[4096];   // 32 KiB
    __shared__ float4 coef[64];    // staged gate coefficients (1 KiB)
    const int tid = threadIdx.x;
    const int bb  = blockIdx.x >> 4;
    const unsigned c = blockIdx.x & 15u;
    const size_t base = (size_t)bb << 16;
    if (tid < 64) coef[tid] = Ug[(size_t)bb * 64 + tid];

    auto expand = [&](unsigned x) -> unsigned {   // gaps ascending, all >= 8
        #pragma unroll
        for (int k = 0; k < 4; ++k) {
            unsigned g = meta.gap[k];
            x = ((x >> g) << (g + 1)) | (x & ((1u << g) - 1u)) | (((c >> k) & 1u) << g);
        }
        return x;
    };

    if constexpr (MODE == 0) {
        __syncthreads();   // coef ready
        if (tid == 0) {
            float2 k = make_float2(1.f, 0.f);
            for (int t = 0; t < 4; ++t) {
                float4 u = coef[meta.nlw[t]];
                float2 col = ((c >> t) & 1u) ? make_float2(-u.z, u.w)
                                             : make_float2(u.x, u.y);
                k = cmul2(k, col);
            }
            amp[0] = v2f{k.x, k.y};
        }
        __syncthreads();
        for (int s = 0; s < 12; ++s) {
            const int n = 1 << s;
            float4 u = coef[meta.wire_of_bit[s]];
            const float2 c0 = make_float2(u.x, u.y);
            const float2 c1 = make_float2(-u.z, u.w);
            for (int i = tid; i < n; i += 256) {
                float2 a = make_float2(amp[i].x, amp[i].y);
                float2 h = cmul2(a, c1);
                float2 l = cmul2(a, c0);
                amp[i + n] = v2f{h.x, h.y};
                amp[i]     = v2f{l.x, l.y};
            }
            __syncthreads();
        }
    } else {
        #pragma unroll
        for (int it = 0; it < 4; ++it) {
            unsigned u = (unsigned)(tid + it * 256) * 4u;
            unsigned a = expand(u);
            uint4 v = *reinterpret_cast<const uint4*>(state + base + a);
            float2 f0 = __half22float2(__builtin_bit_cast(__half2, v.x));
            float2 f1 = __half22float2(__builtin_bit_cast(__half2, v.y));
            float2 f2 = __half22float2(__builtin_bit_cast(__half2, v.z));
            float2 f3 = __half22float2(__builtin_bit_cast(__half2, v.w));
            amp[u + 0] = v2f{f0.x, f0.y};
            amp[u + 1] = v2f{f1.x, f1.y};
            amp[u + 2] = v2f{f2.x, f2.y};
            amp[u + 3] = v2f{f3.x, f3.y};
        }
        __syncthreads();   // also covers coef staging
    }

    for (int ci = 0; ci < meta.nbundles; ++ci) {
        const BundleMeta& B = meta.bd[ci];
        unsigned r = (unsigned)tid;
        #pragma unroll
        for (int k = 0; k < 4; ++k) {
            unsigned p = B.piv[k];
            r = ((r >> p) << (p + 1)) | (r & ((1u << p) - 1u));
        }
        v2f a[16];
        #pragma unroll
        for (int t = 0; t < 16; ++t) a[t] = amp[r ^ B.voff[t]];
        #pragma unroll
        for (int g = 0; g < 4; ++g) {
            if (B.gidx[g] == 0xFF) continue;       // identity pad (uniform skip)
            const float4 uv = coef[B.gidx[g]];
            const unsigned sb = (unsigned)((__popc(r & (unsigned)B.row[g]) +
                                            __popc((unsigned)B.nl[g] & c)) & 1);
            const unsigned fl = B.flip[g];
            #pragma unroll
            for (int t = 0; t < 16; ++t) {
                if (t & (1 << g)) continue;
                unsigned s = (sb ^ ((fl >> t) & 1u)) << 31;
                pair_xor(a[t], a[t ^ (1 << g)], s, uv);
            }
        }
        if (MODE == 2 && ci == meta.nbundles - 1) {
            // measure directly from registers (skip final LDS round-trip)
            float acc = 0.f;
            const unsigned mcp = (unsigned)(__popc((unsigned)meta.meas_nl & c) & 1);
            #pragma unroll
            for (int t = 0; t < 16; ++t) {
                float pr = a[t].x * a[t].x + a[t].y * a[t].y;
                unsigned sg = ((unsigned)__popc((r ^ B.voff[t]) &
                               (unsigned)meta.meas_row) & 1u) ^ mcp;
                acc += sg ? -pr : pr;
            }
            for (int off = 32; off > 0; off >>= 1) acc += __shfl_down(acc, off, 64);
            if ((tid & 63) == 0) atomicAdd(&out[bb], acc);
            return;
        }
        #pragma unroll
        for (int t = 0; t < 16; ++t) amp[r ^ B.voff[t]] = a[t];
        __syncthreads();
    }

    if constexpr (MODE == 2) {
        // fallback (only if nbundles==0): measure from LDS
        float acc = 0.f;
        const unsigned mcp = (unsigned)(__popc((unsigned)meta.meas_nl & c) & 1);
        for (int k = 0; k < 16; ++k) {
            unsigned u = (unsigned)(tid + k * 256);
            v2f a = amp[u];
            float pr = a.x * a.x + a.y * a.y;
            acc += (((unsigned)__popc(u & (unsigned)meta.meas_row) & 1u) ^ mcp)
                 ? -pr : pr;
        }
        for (int off = 32; off > 0; off >>= 1) acc += __shfl_down(acc, off, 64);
        if ((tid & 63) == 0) atomicAdd(&out[bb], acc);
    } else {
        #pragma unroll
        for (int it = 0; it < 4; ++it) {
            unsigned u = (unsigned)(tid + it * 256) * 4u;
            unsigned ad = expand(u);
            __half2 h0 = __float22half2_rn(make_float2(amp[u + 0].x, amp[u + 0].y));
            __half2 h1 = __float22half2_rn(make_float2(amp[u + 1].x, amp[u + 1].y));
            __half2 h2 = __float22half2_rn(make_float2(amp[u + 2].x, amp[u + 2].y));
            __half2 h3 = __float22half2_rn(make_float2(amp[u + 3].x, amp[u + 3].y));
            uint4 v;
            v.x = __builtin_bit_cast(unsigned, h0);
            v.y = __builtin_bit_cast(unsigned, h1);
            v.z = __builtin_bit_cast(unsigned, h2);
            v.w = __builtin_bit_cast(unsigned, h3);
            *reinterpret_cast<uint4*>(state + base + ad) = v;
        }
    }
}

extern "C" void kernel_launch(void* const* d_in, const int* in_sizes, int n_in,
                              void* d_out, int out_size, void* d_ws, size_t ws_size,
                              hipStream_t stream)
{
    const float* X  = (const float*)d_in[0];
    const float* Wt = (const float*)d_in[1];
    const float* Bs = (const float*)d_in[2];
    float* out = (float*)d_out;

    const size_t UG_BYTES = (size_t)512 * 64 * sizeof(float4);  // 512 KiB
    float4*  Ug    = (float4*)d_ws;
    __half2* state = (__half2*)((char*)d_ws + UG_BYTES);
    size_t avail = ws_size > UG_BYTES ? ws_size - UG_BYTES : 0;
    int group = 1;   // fp16 state: 256 KiB per batch element
    while (group < 512 && (size_t)(group * 2) * (65536ull * 4) <= avail)
        group <<= 1;
    const int ngroups = 512 / group;

    // ---- GF(2) bookkeeping (sequential CNOT ring, matches reference) ----
    uint16_t D[16], R[16];
    for (int w = 0; w < 16; ++w) { D[w] = R[w] = (uint16_t)(1u << w); }
    struct G { uint16_t D, R; uint8_t gidx; bool kept; bool sched; };
    G gl[48]; int ng = 0;
    for (int l = 1; l <= 3; ++l) {
        for (int w = 0; w < 16; ++w) { int t = (w + 1) & 15; D[w] ^= D[t]; R[t] ^= R[w]; }
        for (int w = 0; w < 16; ++w)
            gl[ng++] = G{D[w], R[w], (uint8_t)(l * 16 + w), true, false};
    }
    for (int w = 0; w < 16; ++w) { int t = (w + 1) & 15; D[w] ^= D[t]; R[t] ^= R[w]; }
    const uint16_t Rmeas = R[0];

    // Backward prune
    {
        uint16_t keptD[49], keptR[49]; int nk = 0;
        keptD[nk] = 0; keptR[nk] = Rmeas; ++nk;
        for (int i = ng - 1; i >= 0; --i) {
            bool comm = true;
            for (int k = 0; k < nk; ++k) {
                if (__builtin_parity((unsigned)(gl[i].D & keptR[k])) ||
                    __builtin_parity((unsigned)(keptD[k] & gl[i].R))) { comm = false; break; }
            }
            if (comm) gl[i].kept = false;
            else { keptD[nk] = gl[i].D; keptR[nk] = gl[i].R; ++nk; }
        }
    }
    int nkept = 0;
    for (int i = 0; i < ng; ++i) if (gl[i].kept) ++nkept;

    auto commute = [&](int i, int j) -> bool {
        return !(__builtin_parity((unsigned)(gl[i].D & gl[j].R)) ||
                 __builtin_parity((unsigned)(gl[j].D & gl[i].R)));
    };

    const int MAXP = 8;
    auto simulate = [&](uint16_t SA, uint16_t SB, int* passOf) -> int {
        for (int i = 0; i < ng; ++i) gl[i].sched = false;
        int rem = nkept, np = 0, stall = 0;
        while (rem > 0 && np < MAXP) {
            uint16_t S = (np & 1) ? SB : SA;
            int got = 0;
            for (int i = 0; i < ng; ++i) {
                if (!gl[i].kept || gl[i].sched) continue;
                if (gl[i].D & S) continue;
                bool ok = true;
                for (int j = 0; j < i; ++j) {
                    if (!gl[j].kept || gl[j].sched) continue;
                    if (!commute(i, j)) { ok = false; break; }
                }
                if (!ok) continue;
                gl[i].sched = true; --rem; ++got;
                if (passOf) passOf[i] = np;
            }
            ++np;
            if (got == 0) { if (++stall >= 2) break; } else stall = 0;
        }
        return rem == 0 ? np : 99;
    };

    // Window-pair search (LB=12: 4 excluded wires per window, consecutive runs)
    int bestNp = 99, bestA = 0, bestB = 8;
    for (int a = 0; a < 16; ++a) {
        for (int b = 0; b < 16; ++b) {
            uint16_t SA = 0, SB = 0;
            for (int k = 0; k < 4; ++k) {
                SA |= (uint16_t)(1u << ((a + k) & 15));
                SB |= (uint16_t)(1u << ((b + k) & 15));
            }
            int np = simulate(SA, SB, nullptr);
            if (np < bestNp) { bestNp = np; bestA = a; bestB = b; }
        }
    }
    uint16_t SA = 0, SB = 0;
    int exA[4], exB[4];
    for (int k = 0; k < 4; ++k) {
        exA[k] = (bestA + k) & 15; exB[k] = (bestB + k) & 15;
        SA |= (uint16_t)(1u << exA[k]); SB |= (uint16_t)(1u << exB[k]);
    }
    int passOf[48];
    for (int i = 0; i < ng; ++i) passOf[i] = -1;
    int np = simulate(SA, SB, passOf);
    if (np > MAXP) np = MAXP;
    if (np < 2) np = 2;

    // Wire -> bit position: all excluded wires at positions >= 8.
    int wireToPos[16]; bool used[16] = {};
    int pos = 15;
    for (int k = 0; k < 4; ++k) { wireToPos[exA[k]] = pos--; used[exA[k]] = true; }
    for (int k = 0; k < 4; ++k)
        if (!used[exB[k]]) { wireToPos[exB[k]] = pos--; used[exB[k]] = true; }
    for (int w = 0; w < 16; ++w) if (!used[w]) wireToPos[w] = pos--;
    int posToWire[16];
    for (int w = 0; w < 16; ++w) posToWire[wireToPos[w]] = w;

    PassMeta pms[8];
    for (int p = 0; p < np; ++p) {
        PassMeta& M = pms[p];
        memset(&M, 0, sizeof(M));
        const int* ex = (p & 1) ? exB : exA;
        int gp[4], gw[4];
        for (int k = 0; k < 4; ++k) { gp[k] = wireToPos[ex[k]]; gw[k] = ex[k]; }
        for (int a2 = 0; a2 < 4; ++a2)
            for (int b2 = a2 + 1; b2 < 4; ++b2)
                if (gp[b2] < gp[a2]) {
                    int t = gp[a2]; gp[a2] = gp[b2]; gp[b2] = t;
                    t = gw[a2]; gw[a2] = gw[b2]; gw[b2] = t;
                }
        for (int k = 0; k < 4; ++k) { M.gap[k] = (uint8_t)gp[k]; M.nlw[k] = (uint8_t)gw[k]; }
        int packedOfWire[16];
        for (int w = 0; w < 16; ++w) packedOfWire[w] = -1;
        int t = 0;
        for (int q = 0; q < 16; ++q) {
            bool isgap = false;
            for (int k = 0; k < 4; ++k) if (q == gp[k]) isgap = true;
            if (isgap) continue;
            M.wire_of_bit[t] = (uint8_t)posToWire[q];
            packedOfWire[posToWire[q]] = t;
            ++t;
        }
        // local gate list (order preserved from simulate's schedule order)
        struct LG { uint16_t m, r; uint8_t nl, gidx; };
        LG ls[48]; int nsel = 0;
        for (int i = 0; i < ng; ++i) {
            if (!gl[i].kept || passOf[i] != p) continue;
            uint16_t m = 0, r = 0; uint8_t nl = 0;
            for (int w = 0; w < 16; ++w) {
                if ((gl[i].D >> w) & 1) m |= (uint16_t)(1u << packedOfWire[w]);
                if (((gl[i].R >> w) & 1) && packedOfWire[w] >= 0)
                    r |= (uint16_t)(1u << packedOfWire[w]);
            }
            for (int k = 0; k < 4; ++k)
                if ((gl[i].R >> gw[k]) & 1) nl |= (uint8_t)(1u << k);
            ls[nsel++] = LG{m, r, nl, gl[i].gidx};
        }
        // bundle into groups of <=4 with independent masks (consecutive)
        M.nbundles = 0;
        int s = 0;
        while (s < nsel && M.nbundles < 24) {
            BundleMeta& B = M.bd[M.nbundles++];
            for (int j = 0; j < 4; ++j) {
                B.gidx[j] = 0xFF; B.row[j] = 0; B.flip[j] = 0; B.nl[j] = 0;
            }
            uint16_t red[4], om[4]; int pv[4]; int nsl = 0;
            while (nsl < 4 && s < nsel) {
                uint16_t r0 = ls[s].m;
                for (int j = 0; j < nsl; ++j)
                    if ((r0 >> pv[j]) & 1) r0 ^= red[j];
                if (!r0) break;    // dependent -> close bundle
                pv[nsl] = 31 - __builtin_clz((unsigned)r0);
                red[nsl] = r0; om[nsl] = ls[s].m;
                B.gidx[nsl] = ls[s].gidx; B.row[nsl] = ls[s].r; B.nl[nsl] = ls[s].nl;
                ++nsl; ++s;
            }
            for (int b = 11; b >= 0 && nsl < 4; --b) {   // pad basis
                uint16_t r0 = (uint16_t)(1u << b);
                for (int j = 0; j < nsl; ++j)
                    if ((r0 >> pv[j]) & 1) r0 ^= red[j];
                if (!r0) continue;
                pv[nsl] = 31 - __builtin_clz((unsigned)r0);
                red[nsl] = r0; om[nsl] = (uint16_t)(1u << b);
                ++nsl;
            }
            for (int tt = 0; tt < 16; ++tt) {
                uint16_t v = 0;
                for (int j = 0; j < 4; ++j) if ((tt >> j) & 1) v ^= om[j];
                B.voff[tt] = v;
            }
            for (int j = 0; j < 4; ++j) {
                if (B.gidx[j] == 0xFF) continue;
                uint16_t f = 0;
                for (int tt = 0; tt < 16; ++tt)
                    if (__builtin_parity((unsigned)(B.voff[tt] & B.row[j])))
                        f |= (uint16_t)(1u << tt);
                B.flip[j] = f;
            }
            for (int a2 = 0; a2 < 4; ++a2)
                for (int b2 = a2 + 1; b2 < 4; ++b2)
                    if (pv[b2] < pv[a2]) { int tt = pv[a2]; pv[a2] = pv[b2]; pv[b2] = tt; }
            for (int j = 0; j < 4; ++j) B.piv[j] = (uint8_t)pv[j];
        }
        {   // measurement masks (used only if this pass is last)
            uint16_t r = 0; uint8_t nl = 0;
            for (int w = 0; w < 16; ++w)
                if (((Rmeas >> w) & 1) && packedOfWire[w] >= 0)
                    r |= (uint16_t)(1u << packedOfWire[w]);
            for (int k = 0; k < 4; ++k)
                if ((Rmeas >> gw[k]) & 1) nl |= (uint8_t)(1u << k);
            M.meas_row = r; M.meas_nl = nl;
        }
    }

    precompute_kernel<<<dim3(64), dim3(512), 0, stream>>>(X, Wt, Bs, Ug, out);
    for (int g = 0; g < ngroups; ++g) {
        const float4* ug = Ug + (size_t)g * group * 64;
        float* og = out + (size_t)g * group;
        dim3 grid((unsigned)(group << 4));
        for (int p = 0; p < np; ++p) {
            int mode = (p == 0) ? 0 : ((p == np - 1) ? 2 : 1);
            if (mode == 0)
                pass_kernel<0><<<grid, dim3(256), 0, stream>>>(ug, state, og, pms[p]);
            else if (mode == 1)
                pass_kernel<1><<<grid, dim3(256), 0, stream>>>(ug, state, og, pms[p]);
            else
                pass_kernel<2><<<grid, dim3(256), 0, stream>>>(ug, state, og, pms[p]);
        }
    }

    (void)in_sizes; (void)n_in; (void)out_size; (void)ws_size;
}

// Round 6
// 523.210 us; speedup vs baseline: 1.8152x; 1.3103x over previous
//
#include <hip/hip_runtime.h>
#include <hip/hip_fp16.h>
#include <cstdint>
#include <cstring>

// VQR circuit simulator: 16 qubits, B=512, 4 layers.
// CNOTs are GF(2) index-relabeling bookkeeping. Fused 1q gates (SU(2)) are
// XOR-mask pair rotations. Host schedules gates into 2 window passes
// (gen+gates+store, load+gates+measure); within a pass, bundles of 4
// mask-independent gates; each thread applies a bundle on a dim-4 coset
// (16 amps) held in SCALAR registers. __launch_bounds__(256,4) gives the
// compiler 128 VGPRs (LDS caps occupancy at 4 blocks/CU anyway).

struct BundleMeta {
    uint16_t voff[16];   // coset offsets (local 12-bit index space)
    uint16_t row[4];     // branch parity masks (local bits), per slot
    uint16_t flip[4];    // flip[g] bit t = parity(voff[t] & row[g])
    uint8_t  piv[4];     // pivot bit positions, ASCENDING (rep expansion)
    uint8_t  gidx[4];    // gate coefficient index l*16+w; 0xFF = identity pad
    uint8_t  nl[4];      // branch parity masks over the 4 chunk bits
};

struct PassMeta {
    int       nbundles;
    BundleMeta bd[24];
    uint8_t   gap[4];          // non-local bit positions, ASCENDING (all >=8)
    uint8_t   nlw[4];          // chunk bit k -> wire
    uint8_t   wire_of_bit[12]; // packed LDS bit -> wire (product-state init)
    uint16_t  meas_row;        // measurement parity mask (local bits)
    uint8_t   meas_nl;         // measurement parity mask (chunk bits)
};

typedef float v2f __attribute__((ext_vector_type(2)));

__device__ __forceinline__ float2 cmul2(float2 a, float2 b) {
    return make_float2(a.x * b.x - a.y * b.y, a.x * b.y + a.y * b.x);
}
__device__ __forceinline__ float xorf(float a, unsigned s) {
    return __uint_as_float(__float_as_uint(a) ^ s);
}

// Fused U = Rz(t2)Ry(t1)Rz(t0)Rx(enc), enc = 2*atan(x); store (a,b) of SU(2).
__global__ __launch_bounds__(512)
void precompute_kernel(const float* __restrict__ X, const float* __restrict__ Wt,
                       const float* __restrict__ Bs, float4* __restrict__ Ug,
                       float* __restrict__ out)
{
    int id = blockIdx.x * 512 + threadIdx.x;
    if (id >= 512 * 64) return;
    int b = id >> 6, lw = id & 63, l = lw >> 4, w = lw & 15;
    float x  = X[b * 16 + w];
    float ce = 1.0f / sqrtf(1.0f + x * x);
    float se = x * ce;
    float t0 = 0.5f * Wt[(l * 16 + w) * 3 + 0];
    float t1 = 0.5f * Wt[(l * 16 + w) * 3 + 1];
    float t2 = 0.5f * Wt[(l * 16 + w) * 3 + 2];
    float c1 = cosf(t1), s1 = sinf(t1);
    float ca = cosf(t0 + t2), sa = sinf(t0 + t2);
    float cb = cosf(t2 - t0), sb = sinf(t2 - t0);
    float2 W00 = make_float2( c1 * ca, -c1 * sa);
    float2 W01 = make_float2(-s1 * cb,  s1 * sb);
    float2 a  = make_float2(W00.x * ce + W01.y * se, W00.y * ce - W01.x * se);
    float2 bb = make_float2(W00.y * se + W01.x * ce, -W00.x * se + W01.y * ce);
    Ug[id] = make_float4(a.x, a.y, bb.x, bb.y);
    if (lw == 0) out[b] = Bs[0];
}

// MODE 0: generate product state + gates + store (fp16)
// MODE 1: load + gates + store (in-place, fp16)
// MODE 2: load + gates + measurement reduce (no store)
template <int MODE>
__global__ __launch_bounds__(256, 4)
void pass_kernel(const float4* __restrict__ Ug, __half2* __restrict__ state,
                 float* __restrict__ out, PassMeta meta)
{
    __shared__ v2f    amp[4096];   // 32 KiB
    __shared__ float4 coef[64];    // staged gate coefficients (1 KiB)
    const int tid = threadIdx.x;
    const int bb  = blockIdx.x >> 4;
    const unsigned c = blockIdx.x & 15u;
    const size_t base = (size_t)bb << 16;
    if (tid < 64) coef[tid] = Ug[(size_t)bb * 64 + tid];

    auto expand = [&](unsigned x) -> unsigned {   // gaps ascending, all >= 8
        #pragma unroll
        for (int k = 0; k < 4; ++k) {
            unsigned g = meta.gap[k];
            x = ((x >> g) << (g + 1)) | (x & ((1u << g) - 1u)) | (((c >> k) & 1u) << g);
        }
        return x;
    };

    if constexpr (MODE == 0) {
        __syncthreads();   // coef ready
        if (tid == 0) {
            float2 k = make_float2(1.f, 0.f);
            for (int t = 0; t < 4; ++t) {
                float4 u = coef[meta.nlw[t]];
                float2 col = ((c >> t) & 1u) ? make_float2(-u.z, u.w)
                                             : make_float2(u.x, u.y);
                k = cmul2(k, col);
            }
            amp[0] = v2f{k.x, k.y};
        }
        __syncthreads();
        for (int s = 0; s < 12; ++s) {
            const int n = 1 << s;
            float4 u = coef[meta.wire_of_bit[s]];
            const float2 c0 = make_float2(u.x, u.y);
            const float2 c1 = make_float2(-u.z, u.w);
            for (int i = tid; i < n; i += 256) {
                float2 a = make_float2(amp[i].x, amp[i].y);
                float2 h = cmul2(a, c1);
                float2 l = cmul2(a, c0);
                amp[i + n] = v2f{h.x, h.y};
                amp[i]     = v2f{l.x, l.y};
            }
            __syncthreads();
        }
    } else {
        #pragma unroll
        for (int it = 0; it < 4; ++it) {
            unsigned u = (unsigned)(tid + it * 256) * 4u;
            unsigned a = expand(u);
            uint4 v = *reinterpret_cast<const uint4*>(state + base + a);
            float2 f0 = __half22float2(__builtin_bit_cast(__half2, v.x));
            float2 f1 = __half22float2(__builtin_bit_cast(__half2, v.y));
            float2 f2 = __half22float2(__builtin_bit_cast(__half2, v.z));
            float2 f3 = __half22float2(__builtin_bit_cast(__half2, v.w));
            amp[u + 0] = v2f{f0.x, f0.y};
            amp[u + 1] = v2f{f1.x, f1.y};
            amp[u + 2] = v2f{f2.x, f2.y};
            amp[u + 3] = v2f{f3.x, f3.y};
        }
        __syncthreads();   // also covers coef staging
    }

    for (int ci = 0; ci < meta.nbundles; ++ci) {
        const BundleMeta& B = meta.bd[ci];
        unsigned r = (unsigned)tid;
        #pragma unroll
        for (int k = 0; k < 4; ++k) {
            unsigned p = B.piv[k];
            r = ((r >> p) << (p + 1)) | (r & ((1u << p) - 1u));
        }
        float ar_[16], ai_[16];
        #pragma unroll
        for (int t = 0; t < 16; ++t) {
            v2f v = amp[r ^ B.voff[t]];
            ar_[t] = v.x; ai_[t] = v.y;
        }
        #pragma unroll
        for (int g = 0; g < 4; ++g) {
            if (B.gidx[g] == 0xFF) continue;       // identity pad (uniform skip)
            const float4 uv = coef[B.gidx[g]];
            const unsigned sb31 =
                ((unsigned)((__popc(r & (unsigned)B.row[g]) +
                             __popc((unsigned)B.nl[g] & c)) & 1)) << 31;
            const float ai_s = xorf(uv.y, sb31);
            const float br_s = xorf(uv.z, sb31);
            const unsigned fl = B.flip[g];
            #pragma unroll
            for (int t = 0; t < 16; ++t) {
                if (t & (1 << g)) continue;
                const int t2 = t | (1 << g);
                const unsigned fb = (fl << (31 - t)) & 0x80000000u;
                const float tai = xorf(ai_s, fb);
                const float tbr = xorf(br_s, fb);
                const float pr = ar_[t],  pi = ai_[t];
                const float qr = ar_[t2], qi = ai_[t2];
                const float npr = __builtin_fmaf(uv.x, pr,
                                  __builtin_fmaf(-tai, pi,
                                  __builtin_fmaf(tbr, qr, -uv.w * qi)));
                const float npi = __builtin_fmaf(uv.x, pi,
                                  __builtin_fmaf( tai, pr,
                                  __builtin_fmaf(tbr, qi,  uv.w * qr)));
                const float nqr = __builtin_fmaf(-tbr, pr,
                                  __builtin_fmaf(-uv.w, pi,
                                  __builtin_fmaf(uv.x, qr,  tai * qi)));
                const float nqi = __builtin_fmaf(-tbr, pi,
                                  __builtin_fmaf( uv.w, pr,
                                  __builtin_fmaf(uv.x, qi, -tai * qr)));
                ar_[t]  = npr; ai_[t]  = npi;
                ar_[t2] = nqr; ai_[t2] = nqi;
            }
        }
        if (MODE == 2 && ci == meta.nbundles - 1) {
            // measure directly from registers (skip final LDS round-trip)
            float acc = 0.f;
            const unsigned mcp = (unsigned)(__popc((unsigned)meta.meas_nl & c) & 1);
            #pragma unroll
            for (int t = 0; t < 16; ++t) {
                float pr = __builtin_fmaf(ar_[t], ar_[t], ai_[t] * ai_[t]);
                unsigned sg = ((unsigned)__popc((r ^ B.voff[t]) &
                               (unsigned)meta.meas_row) & 1u) ^ mcp;
                acc += sg ? -pr : pr;
            }
            for (int off = 32; off > 0; off >>= 1) acc += __shfl_down(acc, off, 64);
            if ((tid & 63) == 0) atomicAdd(&out[bb], acc);
            return;
        }
        #pragma unroll
        for (int t = 0; t < 16; ++t)
            amp[r ^ B.voff[t]] = v2f{ar_[t], ai_[t]};
        __syncthreads();
    }

    if constexpr (MODE == 2) {
        // fallback (only if nbundles==0): measure from LDS
        float acc = 0.f;
        const unsigned mcp = (unsigned)(__popc((unsigned)meta.meas_nl & c) & 1);
        for (int k = 0; k < 16; ++k) {
            unsigned u = (unsigned)(tid + k * 256);
            v2f a = amp[u];
            float pr = a.x * a.x + a.y * a.y;
            acc += (((unsigned)__popc(u & (unsigned)meta.meas_row) & 1u) ^ mcp)
                 ? -pr : pr;
        }
        for (int off = 32; off > 0; off >>= 1) acc += __shfl_down(acc, off, 64);
        if ((tid & 63) == 0) atomicAdd(&out[bb], acc);
    } else {
        #pragma unroll
        for (int it = 0; it < 4; ++it) {
            unsigned u = (unsigned)(tid + it * 256) * 4u;
            unsigned ad = expand(u);
            __half2 h0 = __float22half2_rn(make_float2(amp[u + 0].x, amp[u + 0].y));
            __half2 h1 = __float22half2_rn(make_float2(amp[u + 1].x, amp[u + 1].y));
            __half2 h2 = __float22half2_rn(make_float2(amp[u + 2].x, amp[u + 2].y));
            __half2 h3 = __float22half2_rn(make_float2(amp[u + 3].x, amp[u + 3].y));
            uint4 v;
            v.x = __builtin_bit_cast(unsigned, h0);
            v.y = __builtin_bit_cast(unsigned, h1);
            v.z = __builtin_bit_cast(unsigned, h2);
            v.w = __builtin_bit_cast(unsigned, h3);
            *reinterpret_cast<uint4*>(state + base + ad) = v;
        }
    }
}

extern "C" void kernel_launch(void* const* d_in, const int* in_sizes, int n_in,
                              void* d_out, int out_size, void* d_ws, size_t ws_size,
                              hipStream_t stream)
{
    const float* X  = (const float*)d_in[0];
    const float* Wt = (const float*)d_in[1];
    const float* Bs = (const float*)d_in[2];
    float* out = (float*)d_out;

    const size_t UG_BYTES = (size_t)512 * 64 * sizeof(float4);  // 512 KiB
    float4*  Ug    = (float4*)d_ws;
    __half2* state = (__half2*)((char*)d_ws + UG_BYTES);
    size_t avail = ws_size > UG_BYTES ? ws_size - UG_BYTES : 0;
    int group = 1;   // fp16 state: 256 KiB per batch element
    while (group < 512 && (size_t)(group * 2) * (65536ull * 4) <= avail)
        group <<= 1;
    const int ngroups = 512 / group;

    // ---- GF(2) bookkeeping (sequential CNOT ring, matches reference) ----
    uint16_t D[16], R[16];
    for (int w = 0; w < 16; ++w) { D[w] = R[w] = (uint16_t)(1u << w); }
    struct G { uint16_t D, R; uint8_t gidx; bool kept; bool sched; };
    G gl[48]; int ng = 0;
    for (int l = 1; l <= 3; ++l) {
        for (int w = 0; w < 16; ++w) { int t = (w + 1) & 15; D[w] ^= D[t]; R[t] ^= R[w]; }
        for (int w = 0; w < 16; ++w)
            gl[ng++] = G{D[w], R[w], (uint8_t)(l * 16 + w), true, false};
    }
    for (int w = 0; w < 16; ++w) { int t = (w + 1) & 15; D[w] ^= D[t]; R[t] ^= R[w]; }
    const uint16_t Rmeas = R[0];

    // Backward prune
    {
        uint16_t keptD[49], keptR[49]; int nk = 0;
        keptD[nk] = 0; keptR[nk] = Rmeas; ++nk;
        for (int i = ng - 1; i >= 0; --i) {
            bool comm = true;
            for (int k = 0; k < nk; ++k) {
                if (__builtin_parity((unsigned)(gl[i].D & keptR[k])) ||
                    __builtin_parity((unsigned)(keptD[k] & gl[i].R))) { comm = false; break; }
            }
            if (comm) gl[i].kept = false;
            else { keptD[nk] = gl[i].D; keptR[nk] = gl[i].R; ++nk; }
        }
    }
    int nkept = 0;
    for (int i = 0; i < ng; ++i) if (gl[i].kept) ++nkept;

    auto commute = [&](int i, int j) -> bool {
        return !(__builtin_parity((unsigned)(gl[i].D & gl[j].R)) ||
                 __builtin_parity((unsigned)(gl[j].D & gl[i].R)));
    };

    const int MAXP = 8;
    auto simulate = [&](uint16_t SA, uint16_t SB, int* passOf) -> int {
        for (int i = 0; i < ng; ++i) gl[i].sched = false;
        int rem = nkept, np = 0, stall = 0;
        while (rem > 0 && np < MAXP) {
            uint16_t S = (np & 1) ? SB : SA;
            int got = 0;
            for (int i = 0; i < ng; ++i) {
                if (!gl[i].kept || gl[i].sched) continue;
                if (gl[i].D & S) continue;
                bool ok = true;
                for (int j = 0; j < i; ++j) {
                    if (!gl[j].kept || gl[j].sched) continue;
                    if (!commute(i, j)) { ok = false; break; }
                }
                if (!ok) continue;
                gl[i].sched = true; --rem; ++got;
                if (passOf) passOf[i] = np;
            }
            ++np;
            if (got == 0) { if (++stall >= 2) break; } else stall = 0;
        }
        return rem == 0 ? np : 99;
    };

    // Window-pair search (LB=12: 4 excluded wires per window, consecutive runs)
    int bestNp = 99, bestA = 0, bestB = 8;
    for (int a = 0; a < 16; ++a) {
        for (int b = 0; b < 16; ++b) {
            uint16_t SA = 0, SB = 0;
            for (int k = 0; k < 4; ++k) {
                SA |= (uint16_t)(1u << ((a + k) & 15));
                SB |= (uint16_t)(1u << ((b + k) & 15));
            }
            int np = simulate(SA, SB, nullptr);
            if (np < bestNp) { bestNp = np; bestA = a; bestB = b; }
        }
    }
    uint16_t SA = 0, SB = 0;
    int exA[4], exB[4];
    for (int k = 0; k < 4; ++k) {
        exA[k] = (bestA + k) & 15; exB[k] = (bestB + k) & 15;
        SA |= (uint16_t)(1u << exA[k]); SB |= (uint16_t)(1u << exB[k]);
    }
    int passOf[48];
    for (int i = 0; i < ng; ++i) passOf[i] = -1;
    int np = simulate(SA, SB, passOf);
    if (np > MAXP) np = MAXP;
    if (np < 2) np = 2;

    // Wire -> bit position: all excluded wires at positions >= 8.
    int wireToPos[16]; bool used[16] = {};
    int pos = 15;
    for (int k = 0; k < 4; ++k) { wireToPos[exA[k]] = pos--; used[exA[k]] = true; }
    for (int k = 0; k < 4; ++k)
        if (!used[exB[k]]) { wireToPos[exB[k]] = pos--; used[exB[k]] = true; }
    for (int w = 0; w < 16; ++w) if (!used[w]) wireToPos[w] = pos--;
    int posToWire[16];
    for (int w = 0; w < 16; ++w) posToWire[wireToPos[w]] = w;

    PassMeta pms[8];
    for (int p = 0; p < np; ++p) {
        PassMeta& M = pms[p];
        memset(&M, 0, sizeof(M));
        const int* ex = (p & 1) ? exB : exA;
        int gp[4], gw[4];
        for (int k = 0; k < 4; ++k) { gp[k] = wireToPos[ex[k]]; gw[k] = ex[k]; }
        for (int a2 = 0; a2 < 4; ++a2)
            for (int b2 = a2 + 1; b2 < 4; ++b2)
                if (gp[b2] < gp[a2]) {
                    int t = gp[a2]; gp[a2] = gp[b2]; gp[b2] = t;
                    t = gw[a2]; gw[a2] = gw[b2]; gw[b2] = t;
                }
        for (int k = 0; k < 4; ++k) { M.gap[k] = (uint8_t)gp[k]; M.nlw[k] = (uint8_t)gw[k]; }
        int packedOfWire[16];
        for (int w = 0; w < 16; ++w) packedOfWire[w] = -1;
        int t = 0;
        for (int q = 0; q < 16; ++q) {
            bool isgap = false;
            for (int k = 0; k < 4; ++k) if (q == gp[k]) isgap = true;
            if (isgap) continue;
            M.wire_of_bit[t] = (uint8_t)posToWire[q];
            packedOfWire[posToWire[q]] = t;
            ++t;
        }
        // local gate list (order preserved from simulate's schedule order)
        struct LG { uint16_t m, r; uint8_t nl, gidx; };
        LG ls[48]; int nsel = 0;
        for (int i = 0; i < ng; ++i) {
            if (!gl[i].kept || passOf[i] != p) continue;
            uint16_t m = 0, r = 0; uint8_t nl = 0;
            for (int w = 0; w < 16; ++w) {
                if ((gl[i].D >> w) & 1) m |= (uint16_t)(1u << packedOfWire[w]);
                if (((gl[i].R >> w) & 1) && packedOfWire[w] >= 0)
                    r |= (uint16_t)(1u << packedOfWire[w]);
            }
            for (int k = 0; k < 4; ++k)
                if ((gl[i].R >> gw[k]) & 1) nl |= (uint8_t)(1u << k);
            ls[nsel++] = LG{m, r, nl, gl[i].gidx};
        }
        // bundle into groups of <=4 with independent masks (consecutive)
        M.nbundles = 0;
        int s = 0;
        while (s < nsel && M.nbundles < 24) {
            BundleMeta& B = M.bd[M.nbundles++];
            for (int j = 0; j < 4; ++j) {
                B.gidx[j] = 0xFF; B.row[j] = 0; B.flip[j] = 0; B.nl[j] = 0;
            }
            uint16_t red[4], om[4]; int pv[4]; int nsl = 0;
            while (nsl < 4 && s < nsel) {
                uint16_t r0 = ls[s].m;
                for (int j = 0; j < nsl; ++j)
                    if ((r0 >> pv[j]) & 1) r0 ^= red[j];
                if (!r0) break;    // dependent -> close bundle
                pv[nsl] = 31 - __builtin_clz((unsigned)r0);
                red[nsl] = r0; om[nsl] = ls[s].m;
                B.gidx[nsl] = ls[s].gidx; B.row[nsl] = ls[s].r; B.nl[nsl] = ls[s].nl;
                ++nsl; ++s;
            }
            for (int b = 11; b >= 0 && nsl < 4; --b) {   // pad basis
                uint16_t r0 = (uint16_t)(1u << b);
                for (int j = 0; j < nsl; ++j)
                    if ((r0 >> pv[j]) & 1) r0 ^= red[j];
                if (!r0) continue;
                pv[nsl] = 31 - __builtin_clz((unsigned)r0);
                red[nsl] = r0; om[nsl] = (uint16_t)(1u << b);
                ++nsl;
            }
            for (int tt = 0; tt < 16; ++tt) {
                uint16_t v = 0;
                for (int j = 0; j < 4; ++j) if ((tt >> j) & 1) v ^= om[j];
                B.voff[tt] = v;
            }
            for (int j = 0; j < 4; ++j) {
                if (B.gidx[j] == 0xFF) continue;
                uint16_t f = 0;
                for (int tt = 0; tt < 16; ++tt)
                    if (__builtin_parity((unsigned)(B.voff[tt] & B.row[j])))
                        f |= (uint16_t)(1u << tt);
                B.flip[j] = f;
            }
            for (int a2 = 0; a2 < 4; ++a2)
                for (int b2 = a2 + 1; b2 < 4; ++b2)
                    if (pv[b2] < pv[a2]) { int tt = pv[a2]; pv[a2] = pv[b2]; pv[b2] = tt; }
            for (int j = 0; j < 4; ++j) B.piv[j] = (uint8_t)pv[j];
        }
        {   // measurement masks (used only if this pass is last)
            uint16_t r = 0; uint8_t nl = 0;
            for (int w = 0; w < 16; ++w)
                if (((Rmeas >> w) & 1) && packedOfWire[w] >= 0)
                    r |= (uint16_t)(1u << packedOfWire[w]);
            for (int k = 0; k < 4; ++k)
                if ((Rmeas >> gw[k]) & 1) nl |= (uint8_t)(1u << k);
            M.meas_row = r; M.meas_nl = nl;
        }
    }

    precompute_kernel<<<dim3(64), dim3(512), 0, stream>>>(X, Wt, Bs, Ug, out);
    for (int g = 0; g < ngroups; ++g) {
        const float4* ug = Ug + (size_t)g * group * 64;
        float* og = out + (size_t)g * group;
        dim3 grid((unsigned)(group << 4));
        for (int p = 0; p < np; ++p) {
            int mode = (p == 0) ? 0 : ((p == np - 1) ? 2 : 1);
            if (mode == 0)
                pass_kernel<0><<<grid, dim3(256), 0, stream>>>(ug, state, og, pms[p]);
            else if (mode == 1)
                pass_kernel<1><<<grid, dim3(256), 0, stream>>>(ug, state, og, pms[p]);
            else
                pass_kernel<2><<<grid, dim3(256), 0, stream>>>(ug, state, og, pms[p]);
        }
    }

    (void)in_sizes; (void)n_in; (void)out_size; (void)ws_size;
}